// Round 15
// baseline (542.419 us; speedup 1.0000x reference)
//
#include <hip/hip_runtime.h>

// FlowNetC correlation, B=8 C=256 H=64 W=128, 9x9 grid.
// out[b,dy*9+dx,h,w] = (1/256) * sum_c in1[b,c,h,w]*in2[b,c,h+dy-4,w+dx-4]
// (in2 zero-padded by 4 in h,w).
//
// R15 REDESIGN around the measured ceiling: ~21 B/cyc/CU global delivery
// (R5..R14 invariant; m97=22, m201=20, hipBLASLt~26 at their flop/byte).
// Old: block=(b,h,dy) staged 1.18 GB at 2.25 flop/B -> 91us wall. New:
// block=(b, 2-row h-tile), 576 thr, wave=dy: the 10 in2 rows + 2 in1 rows
// are staged ONCE and shared by all 9 dy-waves via LDS -> 402 MB staged
// -> ~31us staging roofline; FMA floor 17.3us; LDS pipe ~23us.
// Mechanics: reg-staged writes (R13-proven) into 132-float-stride rows;
// the 4-float pads double as zero borders for the x-window edge reads AND
// give exactly-2-way (free) bank patterns on window/v1 reads (enumerated).
// NBUF=4, 1 raw s_barrier/phase, per-phase vmcnt(0) on the 3-op reg FIFO
// (1-phase ride ~1160cyc > 900 HBM latency). Buffer reuse distance >= 2
// barriers -> R9 race class structurally gone. Wave 8 stages nothing.
// waves_per_eu(3) -> 170-reg budget (R1/R2: 576-thr default capped at 84).
// Tripwire: WRITE_SIZE == 20736 KB.

namespace {

constexpr int Cc = 256, Hh = 64, Ww = 128;
constexpr int HW = Hh * Ww;          // 8192
constexpr int ND = 81;
constexpr int RSTR = 132;            // LDS row stride: 128 data + 4 zero pad
constexpr int NROW = 48;             // 40 in2 (4ch x 10 rows) + 8 in1 (4ch x 2)
constexpr int BUFSZ = 4 + NROW * RSTR;  // 6340 floats (16B-aligned), guard first
constexpr int NPH = 64;              // 64 phases x 4 channels

__global__ __launch_bounds__(576)
__attribute__((amdgpu_waves_per_eu(3)))
void corr_kernel(const float* __restrict__ in1, const float* __restrict__ in2,
                 float* __restrict__ out) {
  __shared__ __align__(16) float lds[4 * BUFSZ];  // 101440 B

  const int tid = threadIdx.x;
  const int dyw = tid >> 6;        // wave = dy 0..8
  const int lane = tid & 63;
  const int q = lane & 15;         // w-oct: pixels 8q..8q+7
  const int hp = (lane >> 4) & 1;  // output row within tile
  const int cs = lane >> 5;        // channel half of the 4-ch phase

  // XCD swizzle: XCD x gets batch x (32 h-tiles); neighbor tiles share
  // 8/12 staged rows -> L2 hits within the XCD.
  const int bid0 = blockIdx.x;
  const int nb = (bid0 & 7) * 32 + (bid0 >> 3);
  const int b = nb >> 5;
  const int h0 = (nb & 31) << 1;

  // zero guard[0,4) + all row pads [128,132) once; never overwritten
  for (int z = tid; z < 4 * 196; z += 576) {
    const int f = z / 196, r = z - f * 196;
    const int off = (r < 4) ? r : (4 + ((r - 4) >> 2) * RSTR + 128 + ((r - 4) & 3));
    lds[f * BUFSZ + off] = 0.0f;
  }

  // ---- staging assignment: waves 0..7 x 3 ops; op j covers 512B units
  // 6*dyw+2j+(lane>>5). Unit u<40: in2 (ch=u/10, row r=u%10 -> h0-4+r);
  // u>=40: in1 (v=u-40: ch=v>>1, row=v&1 -> h0+row). ----
  const float* gsrc0; const float* gsrc1; const float* gsrc2;
  int dst0, dst1, dst2;
  float m0, m1, m2;
  {
    const float* in1b = in1 + (size_t)b * Cc * HW;
    const float* in2b = in2 + (size_t)b * Cc * HW;
    const float* srcs[3]; int dsts[3]; float ms[3];
#pragma unroll
    for (int j = 0; j < 3; ++j) {
      int u = 6 * dyw + 2 * j + (lane >> 5);
      if (u >= 48) u -= 48;  // wave 8: values unused (guarded by dyw<8)
      int k, ch, grow; const float* base; float m = 1.0f;
      if (u < 40) {
        ch = u / 10; const int r = u - ch * 10;
        grow = h0 - 4 + r;
        if ((unsigned)grow >= (unsigned)Hh) { m = 0.0f; grow = 0; }
        base = in2b; k = ch * 10 + r;
      } else {
        const int v = u - 40; ch = v >> 1; const int r = v & 1;
        grow = h0 + r; base = in1b; k = 40 + ch * 2 + r;
      }
      srcs[j] = base + (size_t)ch * HW + (size_t)grow * Ww + 4 * (lane & 31);
      dsts[j] = 4 + k * RSTR + 4 * (lane & 31);
      ms[j] = m;
    }
    gsrc0 = srcs[0]; gsrc1 = srcs[1]; gsrc2 = srcs[2];
    dst0 = dsts[0]; dst1 = dsts[1]; dst2 = dsts[2];
    m0 = ms[0]; m1 = ms[1]; m2 = ms[2];
  }

  // ---- compute read offsets: channels cc=2cs+j; window spans x 8q-4..8q+11
  // (pads supply zeros at both edges); v1 = in1[cc][hp][8q..8q+7]. ----
  const int win0 = 4 + ((2 * cs) * 10 + hp + dyw) * RSTR + 8 * q - 4;
  const int win1 = 4 + ((2 * cs + 1) * 10 + hp + dyw) * RSTR + 8 * q - 4;
  const int v1o0 = 4 + (40 + (2 * cs) * 2 + hp) * RSTR + 8 * q;
  const int v1o1 = 4 + (40 + (2 * cs + 1) * 2 + hp) * RSTR + 8 * q;

  float4 g0, g1, g2;  // staging registers (one phase in flight)

#define LOADP(P)                                                        \
  if (dyw < 8) {                                                        \
    const size_t o_ = (size_t)(P) * 4 * HW;                             \
    g0 = *(const float4*)(gsrc0 + o_);                                  \
    g1 = *(const float4*)(gsrc1 + o_);                                  \
    g2 = *(const float4*)(gsrc2 + o_);                                  \
  }

#define WRITEP(BI)                                                      \
  if (dyw < 8) {                                                        \
    float* L_ = &lds[(BI) * BUFSZ];                                     \
    *(float4*)(L_ + dst0) = make_float4(g0.x*m0, g0.y*m0, g0.z*m0, g0.w*m0); \
    *(float4*)(L_ + dst1) = make_float4(g1.x*m1, g1.y*m1, g1.z*m1, g1.w*m1); \
    *(float4*)(L_ + dst2) = make_float4(g2.x*m2, g2.y*m2, g2.z*m2, g2.w*m2); \
  }

#define CH_FMA(WOFF, VOFF)                                              \
  {                                                                     \
    const float4 Wa = *(const float4*)(Lb + (WOFF));                    \
    const float4 Wb = *(const float4*)(Lb + (WOFF) + 4);                \
    const float4 Wc = *(const float4*)(Lb + (WOFF) + 8);                \
    const float4 Wd = *(const float4*)(Lb + (WOFF) + 12);               \
    const float4 Va = *(const float4*)(Lb + (VOFF));                    \
    const float4 Vb = *(const float4*)(Lb + (VOFF) + 4);                \
    const float t_[16] = {Wa.x, Wa.y, Wa.z, Wa.w, Wb.x, Wb.y, Wb.z, Wb.w, \
                          Wc.x, Wc.y, Wc.z, Wc.w, Wd.x, Wd.y, Wd.z, Wd.w}; \
    const float v_[8] = {Va.x, Va.y, Va.z, Va.w, Vb.x, Vb.y, Vb.z, Vb.w}; \
    _Pragma("unroll") for (int dx_ = 0; dx_ < 9; ++dx_)                 \
      _Pragma("unroll") for (int px_ = 0; px_ < 8; ++px_)               \
        acc[px_][dx_] = fmaf(v_[px_], t_[px_ + dx_], acc[px_][dx_]);    \
  }

#define COMPUTE(BI)                                                     \
  {                                                                     \
    const float* Lb = &lds[(BI) * BUFSZ];                               \
    CH_FMA(win0, v1o0);                                                 \
    CH_FMA(win1, v1o1);                                                 \
  }

#define VMCNT0 asm volatile("s_waitcnt vmcnt(0)" ::: "memory")
#define LGKM0                                            \
  asm volatile("s_waitcnt lgkmcnt(0)" ::: "memory");     \
  __builtin_amdgcn_sched_barrier(0)
#define BAR                                              \
  __builtin_amdgcn_s_barrier();                          \
  __builtin_amdgcn_sched_barrier(0)

  float acc[8][9];
#pragma unroll
  for (int px = 0; px < 8; ++px)
#pragma unroll
    for (int dx = 0; dx < 9; ++dx) acc[px][dx] = 0.0f;

  // prologue: fill buffers 0,1; leave L(2) in flight; sync pads+writes
  LOADP(0); VMCNT0; WRITEP(0);
  LOADP(1); VMCNT0; WRITEP(1);
  LOADP(2);
  LGKM0; BAR;

  // phase p: retire L(p+2) -> write buf (p+2)&3 -> issue L(p+3) ->
  // lgkm drain (ds_writes + prev compute reads) -> barrier -> compute p.
#pragma unroll 1
  for (int pp = 0; pp < 60; pp += 4) {
    VMCNT0; WRITEP(2); LOADP(pp + 3); LGKM0; BAR; COMPUTE(0);
    VMCNT0; WRITEP(3); LOADP(pp + 4); LGKM0; BAR; COMPUTE(1);
    VMCNT0; WRITEP(0); LOADP(pp + 5); LGKM0; BAR; COMPUTE(2);
    VMCNT0; WRITEP(1); LOADP(pp + 6); LGKM0; BAR; COMPUTE(3);
  }
  VMCNT0; WRITEP(2); LOADP(63); LGKM0; BAR; COMPUTE(0);  // phase 60
  VMCNT0; WRITEP(3); LGKM0; BAR; COMPUTE(1);             // phase 61
  COMPUTE(2);                                            // phase 62
  COMPUTE(3);                                            // phase 63

  // sum the two cs channel-halves (lane ^ 32)
#pragma unroll
  for (int px = 0; px < 8; ++px)
#pragma unroll
    for (int dx = 0; dx < 9; ++dx)
      acc[px][dx] += __shfl_xor(acc[px][dx], 32, 64);

  const float s = 1.0f / 256.0f;
  float* ob =
      out + (((size_t)b * ND + (size_t)dyw * 9) * Hh + (h0 + hp)) * Ww + 8 * q;
  if (cs == 0) {
#pragma unroll
    for (int dx = 0; dx < 5; ++dx) {
      *(float4*)(ob + (size_t)dx * HW) = make_float4(
          acc[0][dx] * s, acc[1][dx] * s, acc[2][dx] * s, acc[3][dx] * s);
      *(float4*)(ob + (size_t)dx * HW + 4) = make_float4(
          acc[4][dx] * s, acc[5][dx] * s, acc[6][dx] * s, acc[7][dx] * s);
    }
  } else {
#pragma unroll
    for (int dx = 4; dx < 9; ++dx) {  // dx=4 written by both halves, same value
      *(float4*)(ob + (size_t)dx * HW) = make_float4(
          acc[0][dx] * s, acc[1][dx] * s, acc[2][dx] * s, acc[3][dx] * s);
      *(float4*)(ob + (size_t)dx * HW + 4) = make_float4(
          acc[4][dx] * s, acc[5][dx] * s, acc[6][dx] * s, acc[7][dx] * s);
    }
  }
}

}  // namespace

extern "C" void kernel_launch(void* const* d_in, const int* in_sizes, int n_in,
                              void* d_out, int out_size, void* d_ws,
                              size_t ws_size, hipStream_t stream) {
  (void)in_sizes; (void)n_in; (void)out_size; (void)d_ws; (void)ws_size;
  const float* in1 = (const float*)d_in[0];
  const float* in2 = (const float*)d_in[1];
  float* outp = (float*)d_out;
  corr_kernel<<<256, 576, 0, stream>>>(in1, in2, outp);
}

// Round 16
// 118.318 us; speedup vs baseline: 4.5844x; 4.5844x over previous
//
#include <hip/hip_runtime.h>

// FlowNetC correlation, B=8 C=256 H=64 W=128, 9x9 grid.
// out[b,dy*9+dx,h,w] = (1/256) * sum_c in1[b,c,h,w]*in2[b,c,h+dy-4,w+dx-4]
// (in2 zero-padded by 4 in h,w).
//
// R16: traffic-sharing redesign in the PROVEN 256-thread shape (576-thread
// blocks always hit the 84-reg allocator cliff: R1/R2/R15 all spilled).
// Block = (b, 2-row h-tile, dy-triple g): 768 blocks x 256 thr.
// Thread = (q:16, cs:2, hp:2); wave = dq; dy = 3g+dq; waves 0-2 compute,
// wave 3 stages-only. Per phase (4 ch): wave w stages ch w = 6 rows
// (4 in2 [h0+3g-4+r] + 2 in1 [h0,h0+1]) x 2 halves = 12 width-4
// global_load_lds -> uniform FIFO -> counted VMCNT(24) keeps 2 phases in
// flight. Rows/output-unit = 1 vs R13's 2 -> staged 590 MB vs 1.18 GB
// (measured ceiling ~21 B/cyc/CU of per-CU global delivery -> ~46us floor).
// 132-stride rows: pad[128..132) + guard[0..4) are permanent zeros = window
// x-borders AND OOB-dy rows (masked from staging) -> no special-case blocks.
// NBUF=4 + lgkmcnt(0)-before-barrier: staged buffer's prior readers are >=2
// barriers upstream (R9 race class gone). Boundary blocks (6%): vmcnt(0).
// Tripwire: WRITE_SIZE == 20736 KB exactly.

#define AS1 __attribute__((address_space(1)))
#define AS3 __attribute__((address_space(3)))

namespace {

constexpr int Cc = 256, Hh = 64, Ww = 128;
constexpr int HW = Hh * Ww;        // 8192
constexpr int ND = 81;
constexpr int RSTR = 132;          // 128 data + 4 zero pad
constexpr int NROW = 24;           // 4 ch x (4 in2 + 2 in1)
constexpr int BUFSZ = 4 + NROW * RSTR;  // 3172 floats (4-float guard first)
constexpr int NBUF = 4;

__device__ __forceinline__ void async4(const float* g, float* l) {
  __builtin_amdgcn_global_load_lds((const AS1 unsigned int*)g,
                                   (AS3 unsigned int*)l, 4, 0, 0);
}

#define SBARC __builtin_amdgcn_sched_barrier(0)

template <int BND>
__device__ __forceinline__ void corr_body(const float* __restrict__ in1,
                                          const float* __restrict__ in2,
                                          float* __restrict__ out, int b,
                                          int h0, int g, int tid, float* lds) {
  const int lane = tid & 63;
  const int q = lane & 15;
  const int cs = (lane >> 4) & 1;
  const int hp = lane >> 5;
  const int w = tid >> 6;  // wave id = dq; wave 3 = staging-only

  // zero all buffers once: guard+pads+masked rows stay zero forever
  // (staging only ever writes floats [0,128) of valid rows)
  for (int z = tid; z < NBUF * BUFSZ; z += 256) lds[z] = 0.0f;
  __syncthreads();

  const int rowbase = h0 + 3 * g - 4;  // global row of in2 layout-row 0
  unsigned mvalid = 0;
#pragma unroll
  for (int r = 0; r < 4; ++r)
    if ((unsigned)(rowbase + r) < (unsigned)Hh) mvalid |= 1u << r;

  // per-wave staging sources (phase 0, channel w); per-lane +lane offset.
  const float* s2 = in2 + ((size_t)(b * Cc + w) * Hh + rowbase) * Ww + lane;
  const float* s1 = in1 + ((size_t)(b * Cc + w) * Hh + h0) * Ww + lane;

#define STAGE(P, BI)                                                     \
  {                                                                      \
    const float* a2_ = s2 + (size_t)(P) * 4 * HW;                        \
    const float* a1_ = s1 + (size_t)(P) * 4 * HW;                        \
    float* Lb_ = lds + (BI) * BUFSZ + 4 + w * 6 * RSTR;                  \
    _Pragma("unroll") for (int r_ = 0; r_ < 4; ++r_) {                   \
      if (mvalid & (1u << r_)) {                                         \
        async4(a2_ + r_ * Ww, Lb_ + r_ * RSTR);                          \
        async4(a2_ + r_ * Ww + 64, Lb_ + r_ * RSTR + 64);                \
      }                                                                  \
    }                                                                    \
    _Pragma("unroll") for (int r_ = 0; r_ < 2; ++r_) {                   \
      async4(a1_ + r_ * Ww, Lb_ + (4 + r_) * RSTR);                      \
      async4(a1_ + r_ * Ww + 64, Lb_ + (4 + r_) * RSTR + 64);            \
    }                                                                    \
  }

  // wait: retire through phase p (non-bnd: keep newest 2 phases = N ops);
  // then drain own ds-reads (cross-wave overwrite safety) and barrier.
#define WAITB(N)                                                         \
  {                                                                      \
    if constexpr (BND) {                                                 \
      asm volatile("s_waitcnt vmcnt(0)" ::: "memory");                   \
    } else {                                                             \
      asm volatile("s_waitcnt vmcnt(" #N ")" ::: "memory");              \
    }                                                                    \
    asm volatile("s_waitcnt lgkmcnt(0)" ::: "memory");                   \
    SBARC;                                                               \
    __builtin_amdgcn_s_barrier();                                        \
    SBARC;                                                               \
  }

#define COMPUTE(BI)                                                      \
  if (w < 3) {                                                           \
    const float* Lb_ = lds + (BI) * BUFSZ + 4;                           \
    _Pragma("unroll") for (int j_ = 0; j_ < 2; ++j_) {                   \
      const int ch_ = 2 * cs + j_;                                       \
      const float* wr_ = Lb_ + (ch_ * 6 + hp + w) * RSTR + 8 * q - 4;    \
      const float* vr_ = Lb_ + (ch_ * 6 + 4 + hp) * RSTR + 8 * q;        \
      const float4 A_ = *(const float4*)(wr_);                           \
      const float4 B_ = *(const float4*)(wr_ + 4);                       \
      const float4 C_ = *(const float4*)(wr_ + 8);                       \
      const float4 D_ = *(const float4*)(wr_ + 12);                      \
      const float4 Va_ = *(const float4*)(vr_);                          \
      const float4 Vb_ = *(const float4*)(vr_ + 4);                      \
      const float t_[16] = {A_.x, A_.y, A_.z, A_.w, B_.x, B_.y, B_.z,    \
                            B_.w, C_.x, C_.y, C_.z, C_.w, D_.x, D_.y,    \
                            D_.z, D_.w};                                 \
      const float v_[8] = {Va_.x, Va_.y, Va_.z, Va_.w,                   \
                           Vb_.x, Vb_.y, Vb_.z, Vb_.w};                  \
      _Pragma("unroll") for (int dx_ = 0; dx_ < 9; ++dx_)                \
        _Pragma("unroll") for (int px_ = 0; px_ < 8; ++px_)              \
          acc[px_][dx_] = fmaf(v_[px_], t_[px_ + dx_], acc[px_][dx_]);   \
    }                                                                    \
  }

  float acc[8][9];
#pragma unroll
  for (int px = 0; px < 8; ++px)
#pragma unroll
    for (int dx = 0; dx < 9; ++dx) acc[px][dx] = 0.0f;

  STAGE(0, 0);
  STAGE(1, 1);

  // phase p: issue S(p+2) (buffer re-targeted was computed at p-2, all its
  // readers drained >= 2 barriers ago); WAITB retires S(p); compute p.
#pragma unroll 1
  for (int pp = 0; pp < 60; pp += 4) {
    STAGE(pp + 2, 2); WAITB(24); COMPUTE(0);
    STAGE(pp + 3, 3); WAITB(24); COMPUTE(1);
    STAGE(pp + 4, 0); WAITB(24); COMPUTE(2);
    STAGE(pp + 5, 1); WAITB(24); COMPUTE(3);
  }
  STAGE(62, 2); WAITB(24); COMPUTE(0);  // p=60
  STAGE(63, 3); WAITB(24); COMPUTE(1);  // p=61
  WAITB(12); COMPUTE(2);                // p=62
  WAITB(0);  COMPUTE(3);                // p=63

  if (w < 3) {
    // sum the two cs channel-halves (partner lane^16)
#pragma unroll
    for (int px = 0; px < 8; ++px)
#pragma unroll
      for (int dx = 0; dx < 9; ++dx)
        acc[px][dx] += __shfl_xor(acc[px][dx], 16, 64);

    const int dy = 3 * g + w;
    const float s = 1.0f / 256.0f;
    float* ob =
        out + (((size_t)b * ND + (size_t)dy * 9) * Hh + (h0 + hp)) * Ww + 8 * q;
    if (cs == 0) {
#pragma unroll
      for (int dx = 0; dx < 5; ++dx) {
        *(float4*)(ob + (size_t)dx * HW) = make_float4(
            acc[0][dx] * s, acc[1][dx] * s, acc[2][dx] * s, acc[3][dx] * s);
        *(float4*)(ob + (size_t)dx * HW + 4) = make_float4(
            acc[4][dx] * s, acc[5][dx] * s, acc[6][dx] * s, acc[7][dx] * s);
      }
    } else {
#pragma unroll
      for (int dx = 4; dx < 9; ++dx) {  // dx=4 dup by both halves, same value
        *(float4*)(ob + (size_t)dx * HW) = make_float4(
            acc[0][dx] * s, acc[1][dx] * s, acc[2][dx] * s, acc[3][dx] * s);
        *(float4*)(ob + (size_t)dx * HW + 4) = make_float4(
            acc[4][dx] * s, acc[5][dx] * s, acc[6][dx] * s, acc[7][dx] * s);
      }
    }
  }
}

__global__ __launch_bounds__(256, 3) void corr_kernel(
    const float* __restrict__ in1, const float* __restrict__ in2,
    float* __restrict__ out) {
  __shared__ __align__(16) float lds[NBUF * BUFSZ];  // 50752 B

  // XCD swizzle: XCD x gets nb in [96x, 96x+96) = batch x; the 3 g-blocks
  // of one h-tile are consecutive -> co-resident, sharing rows in L2.
  const int bid0 = blockIdx.x;
  const int nb = (bid0 & 7) * 96 + (bid0 >> 3);
  const int b = nb / 96;
  const int rem = nb - b * 96;
  const int ht = rem / 3;
  const int g = rem - ht * 3;
  const int h0 = ht << 1;

  const bool bnd = (g == 0 && h0 < 4) || (g == 1 && (h0 == 0 || h0 == 62)) ||
                   (g == 2 && h0 > 58);
  if (bnd)
    corr_body<1>(in1, in2, out, b, h0, g, threadIdx.x, lds);
  else
    corr_body<0>(in1, in2, out, b, h0, g, threadIdx.x, lds);
}

}  // namespace

extern "C" void kernel_launch(void* const* d_in, const int* in_sizes, int n_in,
                              void* d_out, int out_size, void* d_ws,
                              size_t ws_size, hipStream_t stream) {
  (void)in_sizes; (void)n_in; (void)out_size; (void)d_ws; (void)ws_size;
  const float* in1 = (const float*)d_in[0];
  const float* in2 = (const float*)d_in[1];
  float* outp = (float*)d_out;
  corr_kernel<<<768, 256, 0, stream>>>(in1, in2, outp);
}